// Round 17
// baseline (96.140 us; speedup 1.0000x reference)
//
#include <hip/hip_runtime.h>
#include <hip/hip_bf16.h>
#include <stdint.h>

typedef __attribute__((ext_vector_type(8))) short short8;
typedef __attribute__((ext_vector_type(4))) float f32x4;
typedef __attribute__((ext_vector_type(4))) int i32x4;
typedef __attribute__((ext_vector_type(2))) int i32x2;
typedef __attribute__((ext_vector_type(4))) unsigned short u16x4;

#define HIDDEN 768
#define HEADS 12
#define HD 64
#define NB 8
#define SEQ 1024
#define MTOT (NB*SEQ)
// Q pre-scale = (1/sqrt(768)) * log2(e): softmax then uses exp2 = raw v_exp_f32
#define QSCALE 0.05205887314427834f

typedef const __attribute__((address_space(1))) uint32_t* gas1_t;
typedef __attribute__((address_space(3))) uint32_t* las3_t;
#define GL_LDS16(g, l) __builtin_amdgcn_global_load_lds((gas1_t)(g), (las3_t)(l), 16, 0, 0)

static __device__ __forceinline__ unsigned short f2bf(float f){
  uint32_t u = __builtin_bit_cast(uint32_t, f);
  u += 0x7fffu + ((u >> 16) & 1u);          // round-to-nearest-even
  return (unsigned short)(u >> 16);
}
static __device__ __forceinline__ float fexp2(float x){
#if __has_builtin(__builtin_amdgcn_exp2f)
  return __builtin_amdgcn_exp2f(x);
#else
  return exp2f(x);
#endif
}

// ---- 1. fp32 -> bf16 convert of hidden_states -------------------------------
__global__ void convert_x_kernel(const float* __restrict__ x, unsigned short* __restrict__ xb){
  int i = blockIdx.x * 256 + threadIdx.x;          // one float4 per thread
  float4 v = reinterpret_cast<const float4*>(x)[i];
  u16x4 o;
  o[0]=f2bf(v.x); o[1]=f2bf(v.y); o[2]=f2bf(v.z); o[3]=f2bf(v.w);
  reinterpret_cast<u16x4*>(xb)[i] = o;
}

// ---- 2. W[k][n] -> Wt[n][k] bf16 (so GEMM B-frags are contiguous in k) ------
__global__ void transpose_w_kernel(const float* __restrict__ Wq, const float* __restrict__ Wk,
                                   const float* __restrict__ Wv, unsigned short* __restrict__ Wt){
  __shared__ float t[32][33];
  int z = blockIdx.z;
  const float* W = (z==0) ? Wq : ((z==1) ? Wk : Wv);
  unsigned short* o = Wt + (size_t)z * HIDDEN * HIDDEN;
  int n0 = blockIdx.x * 32, k0 = blockIdx.y * 32;
  int x = threadIdx.x & 31, y0 = threadIdx.x >> 5;
#pragma unroll
  for(int p=0;p<4;p++){ int y = y0 + p*8; t[y][x] = W[(size_t)(k0+y)*HIDDEN + n0 + x]; }
  __syncthreads();
#pragma unroll
  for(int p=0;p<4;p++){ int y = y0 + p*8; o[(size_t)(n0+y)*HIDDEN + k0 + x] = f2bf(t[x][y]); }
}

// ---- 3. QKV projection GEMM: 64x128 tile, BK=64, swizzled, DOUBLE-BUFFERED --
// ROUND-16 STRUCTURE + T3-minimum dbuf (the ONE change this round):
// STAGE(next tile) -> COMPUTE(cur) -> one __syncthreads per K-step, so the
// prefetch latency hides under 16 MFMA + 12 ds_read of compute. LDS 48 KB ->
// 3 blocks/CU (~= the 2.8 achieved at 24 KB). bf16 Xb + global_load_lds kept
// (round-15's regression was the f32 reg-staging fusion, not the dbuf).
// grid 2304 1D; XCD-panel mapping: 18 blocks sharing an A-panel on one XCD.
// z==0 writes Q pre-scaled by QSCALE; z==2 writes V TRANSPOSED ([bh][d][s]).
__global__ __launch_bounds__(256, 4) void gemm_qkv_kernel(
    const unsigned short* __restrict__ Xb, const unsigned short* __restrict__ Wt,
    const float* __restrict__ bq, const float* __restrict__ bk, const float* __restrict__ bv,
    unsigned short* __restrict__ Qg, unsigned short* __restrict__ Kg, unsigned short* __restrict__ Vt)
{
  __shared__ alignas(16) unsigned short lA[2][64*64];    // 2 x 8 KB
  __shared__ alignas(16) unsigned short lB[2][128*64];   // 2 x 16 KB
  int wgid = blockIdx.x;
  int xcd = wgid & 7, idx = wgid >> 3;       // idx 0..287
  int y = xcd + 8*(idx/18);                  // A-panel id 0..127 (64 rows each)
  int within = idx % 18;
  int xb = within % 6, z = within / 6;
  const unsigned short* W = Wt + (size_t)z*HIDDEN*HIDDEN;
  const float* bias = (z==0) ? bq : ((z==1) ? bk : bv);
  int m0 = y * 64, n0 = xb * 128;
  int tid = threadIdx.x;
  int w = tid >> 6, lane = tid & 63, l16 = lane & 15, g = lane >> 4;
  int wm = w >> 1, wn = w & 1;               // 2x2 wave grid, 32x64 per wave

  // staging per-lane constants (source pre-swizzled: byte^=(row&7)<<4)
  int rs = tid >> 3;
  int cbs = (((tid & 7) << 4) ^ ((rs & 7) << 4)) >> 1;   // element offset
  const unsigned short* gA0 = Xb + (size_t)(m0 + rs)*HIDDEN + cbs;
  const unsigned short* gB0 = W  + (size_t)(n0 + rs)*HIDDEN + cbs;
  const unsigned char* lAb = reinterpret_cast<const unsigned char*>(&lA[0][0]);
  const unsigned char* lBb = reinterpret_cast<const unsigned char*>(&lB[0][0]);

  f32x4 acc[2][4] = {};

#define STAGE(BF, t) do { \
    GL_LDS16(gA0 + (t)*64,                    &lA[BF][0] + w*512); \
    GL_LDS16(gA0 + (size_t)32*HIDDEN + (t)*64, &lA[BF][0] + 2048 + w*512); \
    _Pragma("unroll") for(int p=0;p<4;p++) \
      GL_LDS16(gB0 + (size_t)p*32*HIDDEN + (t)*64, &lB[BF][0] + p*2048 + w*512); \
  } while(0)

#define COMPUTE(CUR) do { _Pragma("unroll") for(int kk=0;kk<2;kk++){ \
    short8 af[2], bf[4]; \
    _Pragma("unroll") for(int i=0;i<2;i++){ \
      int row = wm*32 + i*16 + l16; \
      af[i] = *reinterpret_cast<const short8*>( \
          lAb + (CUR)*8192 + row*128 + ((kk*64 + g*16) ^ ((row&7)<<4))); } \
    _Pragma("unroll") for(int j=0;j<4;j++){ \
      int row = wn*64 + j*16 + l16; \
      bf[j] = *reinterpret_cast<const short8*>( \
          lBb + (CUR)*16384 + row*128 + ((kk*64 + g*16) ^ ((row&7)<<4))); } \
    _Pragma("unroll") for(int i=0;i<2;i++) \
      _Pragma("unroll") for(int j=0;j<4;j++) \
        acc[i][j] = __builtin_amdgcn_mfma_f32_16x16x32_bf16(af[i], bf[j], acc[i][j], 0, 0, 0); \
  } } while(0)

  STAGE(0, 0);
  __syncthreads();                           // drain prologue stage
  for(int t=0; t<12; t++){
    int cur = t & 1;
    if(t < 11) STAGE(cur^1, t+1);            // prefetch next K-tile (other buf)
    COMPUTE(cur);
    __syncthreads();                         // one barrier/iter (drains prefetch)
  }

  if(z == 2){
    // V epilogue: bias then TRANSPOSED write Vt[bh][d][s], 4 consecutive s/lane
#pragma unroll
    for(int i=0;i<2;i++){
      int mb = m0 + wm*32 + i*16 + g*4;
      int b = mb >> 10, s = mb & 1023;       // all 4 rows stay in one (b, s+0..3)
#pragma unroll
      for(int j=0;j<4;j++){
        int n = n0 + wn*64 + j*16 + l16;
        float bi = bias[n];
        int h = n >> 6, d = n & 63;
        u16x4 pk;
#pragma unroll
        for(int r=0;r<4;r++) pk[r] = f2bf(acc[i][j][r] + bi);
        *reinterpret_cast<u16x4*>(Vt + ((size_t)(b*HEADS + h)*HD + d)*SEQ + s) = pk;
      }
    }
  } else {
    unsigned short* out = (z==0) ? Qg : Kg;
#pragma unroll
    for(int i=0;i<2;i++){
      int mb = m0 + wm*32 + i*16 + g*4;
#pragma unroll
      for(int j=0;j<4;j++){
        int n = n0 + wn*64 + j*16 + l16;       // D col = lane&15
        float bi = bias[n];
        int h = n >> 6, d = n & 63;
#pragma unroll
        for(int r=0;r<4;r++){                  // D row = 4*(lane>>4)+r
          int m = mb + r;
          int b = m >> 10, s = m & 1023;
          float cv = acc[i][j][r] + bi;
          if(z == 0) cv *= QSCALE;
          out[((size_t)(b*HEADS + h)*SEQ + s)*HD + d] = f2bf(cv);
        }
      }
    }
  }
#undef STAGE
#undef COMPUTE
}

// ---- 4. flash attention: QBLK=128/block, 4 waves x 32 rows, dbuf K/V --------
// (verified round 14 — unchanged) SWAPPED QK^T: S^T = mfma(A=K, B=Q), q
// lane-local; P^T B-frag lane-local via sigma-permuted contraction axis;
// V^T A-frag reads absorb sigma as two ds_read_b64 per (jn,m); XOR swizzle
// over the FULL within-row offset. Row-sum reduced once in the epilogue.
__global__ __launch_bounds__(256, 3) void attn_kernel(
    const unsigned short* __restrict__ Qg, const unsigned short* __restrict__ Kg,
    const unsigned short* __restrict__ Vt, float* __restrict__ out)
{
  __shared__ alignas(16) unsigned short lK[2][64*64];  // [key][d], XOR-swizzled
  __shared__ alignas(16) unsigned short lV[2][64*64];  // [d][key], XOR-swizzled
  int wgid = blockIdx.x;
  int xcd = wgid & 7, ix = wgid >> 3;          // xcd = dispatch%8 heuristic
  int bh = xcd*12 + (ix >> 3), qb = ix & 7;    // 12 heads per XCD (3MB K/V < L2)
  int b = bh / HEADS, h = bh % HEADS;
  int tid = threadIdx.x, w = tid >> 6, lane = tid & 63, l16 = lane & 15, g = lane >> 4;

  // Q B-frags (2 row-groups x 2 d-halves) in registers for whole kernel
  const unsigned short* Qbase = Qg + ((size_t)bh*SEQ + qb*128 + w*32)*HD;
  short8 qA0 = *reinterpret_cast<const short8*>(Qbase + l16*HD + g*8);
  short8 qA1 = *reinterpret_cast<const short8*>(Qbase + l16*HD + 32 + g*8);
  short8 qB0 = *reinterpret_cast<const short8*>(Qbase + (16+l16)*HD + g*8);
  short8 qB1 = *reinterpret_cast<const short8*>(Qbase + (16+l16)*HD + 32 + g*8);

  f32x4 oacc[2][4] = {};                       // O^T: [rg][jn] d=16jn+4g+r, q=l16
  float lpart[2] = {0.f, 0.f};                 // per-lane partial row sum (q=l16)

  // per-lane constant LDS addresses (all loop offsets become immediates)
  int sw = (l16 & 7) << 4;
  int ro0 = l16*128 + ((g*16) ^ sw);           // K-frag byte offset, d-half 0
  int ro1 = l16*128 + ((64 + g*16) ^ sw);      // K-frag byte offset, d-half 1
  // V-frag b64 offsets: sigma absorbed; XOR over the FULL within-row offset
  int vo00 = l16*128 + ((      8*g) ^ sw);     // m=0, keys 4g+0..3
  int vo01 = l16*128 + ((32  + 8*g) ^ sw);     // m=0, keys 16+4g+0..3
  int vo10 = l16*128 + ((64  + 8*g) ^ sw);     // m=1, keys 32+4g+0..3
  int vo11 = l16*128 + ((96  + 8*g) ^ sw);     // m=1, keys 48+4g+0..3
  const unsigned char* lKb = reinterpret_cast<const unsigned char*>(&lK[0][0]);
  const unsigned char* lVb = reinterpret_cast<const unsigned char*>(&lV[0][0]);

  // per-lane constant staging addresses (source pre-swizzled: byte^=(row&7)<<4)
  int r0 = tid >> 3;
  int cb0 = (((tid & 7) << 4) ^ ((r0 & 7) << 4)) >> 1;             // elements
  const unsigned short* gK0 = Kg + (size_t)bh*SEQ*HD + r0*HD + cb0;
  const unsigned short* gV0 = Vt + (size_t)bh*HD*SEQ + r0*SEQ + cb0;

#define STAGE(B, t) do { \
    GL_LDS16(gK0 + (t)*4096,          &lK[B][0] + w*512); \
    GL_LDS16(gK0 + (t)*4096 + 2048,   &lK[B][0] + 2048 + w*512); \
    GL_LDS16(gV0 + (t)*64,            &lV[B][0] + w*512); \
    GL_LDS16(gV0 + (t)*64 + 32*SEQ,   &lV[B][0] + 2048 + w*512); \
  } while(0)

  // exp2 + lane-local P^T frag build + PV for one row-group
#define SMPV(SREG, LP, OA) do { \
    int Wlo[4], Whi[4]; \
    _Pragma("unroll") for(int j=0;j<4;j++){ \
      float p0=fexp2(SREG[j][0]), p1=fexp2(SREG[j][1]); \
      float p2=fexp2(SREG[j][2]), p3=fexp2(SREG[j][3]); \
      LP += (p0+p1)+(p2+p3); \
      asm("v_cvt_pk_bf16_f32 %0, %1, %2" : "=v"(Wlo[j]) : "v"(p0), "v"(p1)); \
      asm("v_cvt_pk_bf16_f32 %0, %1, %2" : "=v"(Whi[j]) : "v"(p2), "v"(p3)); } \
    _Pragma("unroll") for(int m=0;m<2;m++){ \
      i32x4 cc; cc[0]=Wlo[2*m]; cc[1]=Whi[2*m]; cc[2]=Wlo[2*m+1]; cc[3]=Whi[2*m+1]; \
      short8 pB = __builtin_bit_cast(short8, cc); \
      _Pragma("unroll") for(int jn=0;jn<4;jn++) \
        OA[jn] = __builtin_amdgcn_mfma_f32_16x16x32_bf16(vf[jn][m], pB, OA[jn], 0,0,0); } \
  } while(0)

#define TILE(CUR, kt, HAS_NEXT) do { \
    if(HAS_NEXT) STAGE((CUR)^1, (kt)+1); \
    short8 kf[4][2]; \
    _Pragma("unroll") for(int j=0;j<4;j++){ \
      kf[j][0] = *reinterpret_cast<const short8*>(lKb + (CUR)*8192 + j*2048 + ro0); \
      kf[j][1] = *reinterpret_cast<const short8*>(lKb + (CUR)*8192 + j*2048 + ro1); } \
    short8 vf[4][2]; \
    _Pragma("unroll") for(int jn=0;jn<4;jn++){ \
      { i32x2 vl = *reinterpret_cast<const i32x2*>(lVb + (CUR)*8192 + jn*2048 + vo00); \
        i32x2 vh = *reinterpret_cast<const i32x2*>(lVb + (CUR)*8192 + jn*2048 + vo01); \
        i32x4 vc; vc[0]=vl[0]; vc[1]=vl[1]; vc[2]=vh[0]; vc[3]=vh[1]; \
        vf[jn][0] = __builtin_bit_cast(short8, vc); } \
      { i32x2 vl = *reinterpret_cast<const i32x2*>(lVb + (CUR)*8192 + jn*2048 + vo10); \
        i32x2 vh = *reinterpret_cast<const i32x2*>(lVb + (CUR)*8192 + jn*2048 + vo11); \
        i32x4 vc; vc[0]=vl[0]; vc[1]=vl[1]; vc[2]=vh[0]; vc[3]=vh[1]; \
        vf[jn][1] = __builtin_bit_cast(short8, vc); } } \
    f32x4 s0[4], s1[4]; \
    _Pragma("unroll") for(int j=0;j<4;j++){ \
      f32x4 zz = {}; \
      zz    = __builtin_amdgcn_mfma_f32_16x16x32_bf16(kf[j][0], qA0, zz, 0,0,0); \
      s0[j] = __builtin_amdgcn_mfma_f32_16x16x32_bf16(kf[j][1], qA1, zz, 0,0,0); } \
    _Pragma("unroll") for(int j=0;j<4;j++){ \
      f32x4 zz = {}; \
      zz    = __builtin_amdgcn_mfma_f32_16x16x32_bf16(kf[j][0], qB0, zz, 0,0,0); \
      s1[j] = __builtin_amdgcn_mfma_f32_16x16x32_bf16(kf[j][1], qB1, zz, 0,0,0); } \
    SMPV(s0, lpart[0], oacc[0]); \
    SMPV(s1, lpart[1], oacc[1]); \
    __syncthreads(); \
  } while(0)

  STAGE(0, 0);
  __syncthreads();                             // drains vmcnt before first use

  for(int kt=0; kt<SEQ/64; kt+=2){
    TILE(0, kt, true);
    TILE(1, kt+1, (kt+1) < SEQ/64 - 1);
  }

  // epilogue: reduce row sum across g-lanes (^16, ^32), then O^T/l, f32 store
#pragma unroll
  for(int rg=0;rg<2;rg++){
    float tot = lpart[rg];
    tot += __shfl_xor(tot, 16, 64);
    tot += __shfl_xor(tot, 32, 64);
    float invl = 1.0f / tot;
    int s = qb*128 + w*32 + rg*16 + l16;
    float* orow = out + ((size_t)b*SEQ + s)*HIDDEN + h*HD + 4*g;
#pragma unroll
    for(int jn=0;jn<4;jn++){
      float4 val;
      val.x = oacc[rg][jn][0]*invl; val.y = oacc[rg][jn][1]*invl;
      val.z = oacc[rg][jn][2]*invl; val.w = oacc[rg][jn][3]*invl;
      *reinterpret_cast<float4*>(orow + 16*jn) = val;
    }
  }
#undef STAGE
#undef SMPV
#undef TILE
}

extern "C" void kernel_launch(void* const* d_in, const int* in_sizes, int n_in,
                              void* d_out, int out_size, void* d_ws, size_t ws_size,
                              hipStream_t stream) {
  const float* hs = (const float*)d_in[0];
  const float* Wq = (const float*)d_in[1];
  const float* bq = (const float*)d_in[2];
  const float* Wk = (const float*)d_in[3];
  const float* bk = (const float*)d_in[4];
  const float* Wv = (const float*)d_in[5];
  const float* bv = (const float*)d_in[6];
  float* out = (float*)d_out;

  char* ws = (char*)d_ws;
  unsigned short* Xb = (unsigned short*)ws;                          // 12.6 MB
  unsigned short* Wt = (unsigned short*)(ws + (size_t)12582912);     // 3.5 MB
  unsigned short* Qg = (unsigned short*)(ws + (size_t)16121856);
  unsigned short* Kg = Qg + (size_t)MTOT*HIDDEN;
  unsigned short* Vt = Kg + (size_t)MTOT*HIDDEN;                     // [bh][d][s]

  convert_x_kernel<<<MTOT*HIDDEN/4/256, 256, 0, stream>>>(hs, Xb);
  transpose_w_kernel<<<dim3(24,24,3), 256, 0, stream>>>(Wq, Wk, Wv, Wt);
  gemm_qkv_kernel<<<2304, 256, 0, stream>>>(Xb, Wt, bq, bk, bv, Qg, Kg, Vt);
  attn_kernel<<<768, 256, 0, stream>>>(Qg, Kg, Vt, out);
}

// Round 20
// 94.507 us; speedup vs baseline: 1.0173x; 1.0173x over previous
//
#include <hip/hip_runtime.h>
#include <hip/hip_bf16.h>
#include <stdint.h>

typedef __attribute__((ext_vector_type(8))) short short8;
typedef __attribute__((ext_vector_type(4))) float f32x4;
typedef __attribute__((ext_vector_type(4))) int i32x4;
typedef __attribute__((ext_vector_type(2))) int i32x2;
typedef __attribute__((ext_vector_type(4))) unsigned short u16x4;

#define HIDDEN 768
#define HEADS 12
#define HD 64
#define NB 8
#define SEQ 1024
#define MTOT (NB*SEQ)
// Q pre-scale = (1/sqrt(768)) * log2(e): softmax then uses exp2 = raw v_exp_f32
#define QSCALE 0.05205887314427834f

typedef const __attribute__((address_space(1))) uint32_t* gas1_t;
typedef __attribute__((address_space(3))) uint32_t* las3_t;
#define GL_LDS16(g, l) __builtin_amdgcn_global_load_lds((gas1_t)(g), (las3_t)(l), 16, 0, 0)

static __device__ __forceinline__ unsigned short f2bf(float f){
  uint32_t u = __builtin_bit_cast(uint32_t, f);
  u += 0x7fffu + ((u >> 16) & 1u);          // round-to-nearest-even
  return (unsigned short)(u >> 16);
}
static __device__ __forceinline__ float fexp2(float x){
#if __has_builtin(__builtin_amdgcn_exp2f)
  return __builtin_amdgcn_exp2f(x);
#else
  return exp2f(x);
#endif
}

// ---- 1. fp32 -> bf16 convert of hidden_states -------------------------------
__global__ void convert_x_kernel(const float* __restrict__ x, unsigned short* __restrict__ xb){
  int i = blockIdx.x * 256 + threadIdx.x;          // one float4 per thread
  float4 v = reinterpret_cast<const float4*>(x)[i];
  u16x4 o;
  o[0]=f2bf(v.x); o[1]=f2bf(v.y); o[2]=f2bf(v.z); o[3]=f2bf(v.w);
  reinterpret_cast<u16x4*>(xb)[i] = o;
}

// ---- 2. W[k][n] -> Wt[n][k] bf16 (so GEMM B-frags are contiguous in k) ------
__global__ void transpose_w_kernel(const float* __restrict__ Wq, const float* __restrict__ Wk,
                                   const float* __restrict__ Wv, unsigned short* __restrict__ Wt){
  __shared__ float t[32][33];
  int z = blockIdx.z;
  const float* W = (z==0) ? Wq : ((z==1) ? Wk : Wv);
  unsigned short* o = Wt + (size_t)z * HIDDEN * HIDDEN;
  int n0 = blockIdx.x * 32, k0 = blockIdx.y * 32;
  int x = threadIdx.x & 31, y0 = threadIdx.x >> 5;
#pragma unroll
  for(int p=0;p<4;p++){ int y = y0 + p*8; t[y][x] = W[(size_t)(k0+y)*HIDDEN + n0 + x]; }
  __syncthreads();
#pragma unroll
  for(int p=0;p<4;p++){ int y = y0 + p*8; o[(size_t)(n0+y)*HIDDEN + k0 + x] = f2bf(t[x][y]); }
}

// ---- 3. QKV projection GEMM: 128x256 tile, BK=64, single-buffer 2-barrier ---
// ROUND-14 STRUCTURE (verified best), N-tile doubled 128->256: 64 MFMA +
// 24 ds_read per barrier-pair halves per-FLOP barrier/stall overhead.
// STAGING COVERAGE (r19 bug was A p<2): rows x 8 lanes/row / 256 threads ->
// A: 128 rows = p<4 (16 KB), B: 256 rows = p<8 (32 KB). LDS 48 KB.
// grid 576 1D; XCD-panel mapping: 9 blocks (3 xb x 3 z) sharing a 128-row
// A-panel land on one XCD. LDS rows 128B, both-sides XOR swizzle
// byte^=(row&7)<<4 (pre-swizzled global_load_lds source + swizzled ds_read).
// z==0 writes Q pre-scaled by QSCALE; z==2 writes V TRANSPOSED ([bh][d][s]).
__global__ __launch_bounds__(256, 2) void gemm_qkv_kernel(
    const unsigned short* __restrict__ Xb, const unsigned short* __restrict__ Wt,
    const float* __restrict__ bq, const float* __restrict__ bk, const float* __restrict__ bv,
    unsigned short* __restrict__ Qg, unsigned short* __restrict__ Kg, unsigned short* __restrict__ Vt)
{
  __shared__ alignas(16) unsigned short lA[128*64];   // 16 KB
  __shared__ alignas(16) unsigned short lB[256*64];   // 32 KB
  int wgid = blockIdx.x;
  int xcd = wgid & 7, idx = wgid >> 3;       // idx 0..71
  int y = xcd + 8*(idx/9);                   // A-panel id 0..63 (128 rows each)
  int within = idx % 9;
  int xb = within % 3, z = within / 3;
  const unsigned short* W = Wt + (size_t)z*HIDDEN*HIDDEN;
  const float* bias = (z==0) ? bq : ((z==1) ? bk : bv);
  int m0 = y * 128, n0 = xb * 256;
  int tid = threadIdx.x;
  int w = tid >> 6, lane = tid & 63, l16 = lane & 15, g = lane >> 4;
  int wm = w >> 1, wn = w & 1;               // 2x2 wave grid, 64x128 per wave
  f32x4 acc[4][8] = {};
  for(int kt=0; kt<HIDDEN; kt+=64){
    __syncthreads();
#pragma unroll
    for(int p=0;p<4;p++){                            // A: 128 rows (p<4 !)
      int t2 = p*256 + tid;
      int r = t2 >> 3;
      int cb = (((t2 & 7) << 4) ^ ((r & 7) << 4));
      GL_LDS16(Xb + (size_t)(m0 + r)*HIDDEN + kt + (cb >> 1), lA + p*2048 + w*512);
    }
#pragma unroll
    for(int p=0;p<8;p++){                            // B: 256 rows
      int t2 = p*256 + tid;
      int r = t2 >> 3;
      int cb = (((t2 & 7) << 4) ^ ((r & 7) << 4));
      GL_LDS16(W + (size_t)(n0 + r)*HIDDEN + kt + (cb >> 1), lB + p*2048 + w*512);
    }
    __syncthreads();
#pragma unroll
    for(int kk=0;kk<2;kk++){
      short8 af[4], bf[8];
#pragma unroll
      for(int i=0;i<4;i++){
        int row = wm*64 + i*16 + l16;
        af[i] = *reinterpret_cast<const short8*>(
            reinterpret_cast<const unsigned char*>(lA) + row*128 + ((kk*64 + g*16) ^ ((row&7)<<4)));
      }
#pragma unroll
      for(int j=0;j<8;j++){
        int row = wn*128 + j*16 + l16;
        bf[j] = *reinterpret_cast<const short8*>(
            reinterpret_cast<const unsigned char*>(lB) + row*128 + ((kk*64 + g*16) ^ ((row&7)<<4)));
      }
#pragma unroll
      for(int i=0;i<4;i++)
#pragma unroll
        for(int j=0;j<8;j++)
          acc[i][j] = __builtin_amdgcn_mfma_f32_16x16x32_bf16(af[i], bf[j], acc[i][j], 0, 0, 0);
    }
  }
  if(z == 2){
    // V epilogue: bias then TRANSPOSED write Vt[bh][d][s], 4 consecutive s/lane
#pragma unroll
    for(int i=0;i<4;i++){
      int mb = m0 + wm*64 + i*16 + g*4;
      int b = mb >> 10, s = mb & 1023;       // all 4 rows stay in one (b, s+0..3)
#pragma unroll
      for(int j=0;j<8;j++){
        int n = n0 + wn*128 + j*16 + l16;
        float bi = bias[n];
        int h = n >> 6, d = n & 63;
        u16x4 pk;
#pragma unroll
        for(int r=0;r<4;r++) pk[r] = f2bf(acc[i][j][r] + bi);
        *reinterpret_cast<u16x4*>(Vt + ((size_t)(b*HEADS + h)*HD + d)*SEQ + s) = pk;
      }
    }
  } else {
    unsigned short* out = (z==0) ? Qg : Kg;
#pragma unroll
    for(int i=0;i<4;i++){
      int mb = m0 + wm*64 + i*16 + g*4;
#pragma unroll
      for(int j=0;j<8;j++){
        int n = n0 + wn*128 + j*16 + l16;      // D col = lane&15
        float bi = bias[n];
        int h = n >> 6, d = n & 63;
#pragma unroll
        for(int r=0;r<4;r++){                  // D row = 4*(lane>>4)+r
          int m = mb + r;
          int b = m >> 10, s = m & 1023;
          float cv = acc[i][j][r] + bi;
          if(z == 0) cv *= QSCALE;
          out[((size_t)(b*HEADS + h)*SEQ + s)*HD + d] = f2bf(cv);
        }
      }
    }
  }
}

// ---- 4. flash attention: QBLK=128/block, 4 waves x 32 rows, dbuf K/V --------
// (verified round 14 — unchanged) SWAPPED QK^T: S^T = mfma(A=K, B=Q), q
// lane-local; P^T B-frag lane-local via sigma-permuted contraction axis;
// V^T A-frag reads absorb sigma as two ds_read_b64 per (jn,m); XOR swizzle
// over the FULL within-row offset. Row-sum reduced once in the epilogue.
__global__ __launch_bounds__(256, 3) void attn_kernel(
    const unsigned short* __restrict__ Qg, const unsigned short* __restrict__ Kg,
    const unsigned short* __restrict__ Vt, float* __restrict__ out)
{
  __shared__ alignas(16) unsigned short lK[2][64*64];  // [key][d], XOR-swizzled
  __shared__ alignas(16) unsigned short lV[2][64*64];  // [d][key], XOR-swizzled
  int wgid = blockIdx.x;
  int xcd = wgid & 7, ix = wgid >> 3;          // xcd = dispatch%8 heuristic
  int bh = xcd*12 + (ix >> 3), qb = ix & 7;    // 12 heads per XCD (3MB K/V < L2)
  int b = bh / HEADS, h = bh % HEADS;
  int tid = threadIdx.x, w = tid >> 6, lane = tid & 63, l16 = lane & 15, g = lane >> 4;

  // Q B-frags (2 row-groups x 2 d-halves) in registers for whole kernel
  const unsigned short* Qbase = Qg + ((size_t)bh*SEQ + qb*128 + w*32)*HD;
  short8 qA0 = *reinterpret_cast<const short8*>(Qbase + l16*HD + g*8);
  short8 qA1 = *reinterpret_cast<const short8*>(Qbase + l16*HD + 32 + g*8);
  short8 qB0 = *reinterpret_cast<const short8*>(Qbase + (16+l16)*HD + g*8);
  short8 qB1 = *reinterpret_cast<const short8*>(Qbase + (16+l16)*HD + 32 + g*8);

  f32x4 oacc[2][4] = {};                       // O^T: [rg][jn] d=16jn+4g+r, q=l16
  float lpart[2] = {0.f, 0.f};                 // per-lane partial row sum (q=l16)

  // per-lane constant LDS addresses (all loop offsets become immediates)
  int sw = (l16 & 7) << 4;
  int ro0 = l16*128 + ((g*16) ^ sw);           // K-frag byte offset, d-half 0
  int ro1 = l16*128 + ((64 + g*16) ^ sw);      // K-frag byte offset, d-half 1
  // V-frag b64 offsets: sigma absorbed; XOR over the FULL within-row offset
  int vo00 = l16*128 + ((      8*g) ^ sw);     // m=0, keys 4g+0..3
  int vo01 = l16*128 + ((32  + 8*g) ^ sw);     // m=0, keys 16+4g+0..3
  int vo10 = l16*128 + ((64  + 8*g) ^ sw);     // m=1, keys 32+4g+0..3
  int vo11 = l16*128 + ((96  + 8*g) ^ sw);     // m=1, keys 48+4g+0..3
  const unsigned char* lKb = reinterpret_cast<const unsigned char*>(&lK[0][0]);
  const unsigned char* lVb = reinterpret_cast<const unsigned char*>(&lV[0][0]);

  // per-lane constant staging addresses (source pre-swizzled: byte^=(row&7)<<4)
  int r0 = tid >> 3;
  int cb0 = (((tid & 7) << 4) ^ ((r0 & 7) << 4)) >> 1;             // elements
  const unsigned short* gK0 = Kg + (size_t)bh*SEQ*HD + r0*HD + cb0;
  const unsigned short* gV0 = Vt + (size_t)bh*HD*SEQ + r0*SEQ + cb0;

#define STAGE(B, t) do { \
    GL_LDS16(gK0 + (t)*4096,          &lK[B][0] + w*512); \
    GL_LDS16(gK0 + (t)*4096 + 2048,   &lK[B][0] + 2048 + w*512); \
    GL_LDS16(gV0 + (t)*64,            &lV[B][0] + w*512); \
    GL_LDS16(gV0 + (t)*64 + 32*SEQ,   &lV[B][0] + 2048 + w*512); \
  } while(0)

  // exp2 + lane-local P^T frag build + PV for one row-group
#define SMPV(SREG, LP, OA) do { \
    int Wlo[4], Whi[4]; \
    _Pragma("unroll") for(int j=0;j<4;j++){ \
      float p0=fexp2(SREG[j][0]), p1=fexp2(SREG[j][1]); \
      float p2=fexp2(SREG[j][2]), p3=fexp2(SREG[j][3]); \
      LP += (p0+p1)+(p2+p3); \
      asm("v_cvt_pk_bf16_f32 %0, %1, %2" : "=v"(Wlo[j]) : "v"(p0), "v"(p1)); \
      asm("v_cvt_pk_bf16_f32 %0, %1, %2" : "=v"(Whi[j]) : "v"(p2), "v"(p3)); } \
    _Pragma("unroll") for(int m=0;m<2;m++){ \
      i32x4 cc; cc[0]=Wlo[2*m]; cc[1]=Whi[2*m]; cc[2]=Wlo[2*m+1]; cc[3]=Whi[2*m+1]; \
      short8 pB = __builtin_bit_cast(short8, cc); \
      _Pragma("unroll") for(int jn=0;jn<4;jn++) \
        OA[jn] = __builtin_amdgcn_mfma_f32_16x16x32_bf16(vf[jn][m], pB, OA[jn], 0,0,0); } \
  } while(0)

#define TILE(CUR, kt, HAS_NEXT) do { \
    if(HAS_NEXT) STAGE((CUR)^1, (kt)+1); \
    short8 kf[4][2]; \
    _Pragma("unroll") for(int j=0;j<4;j++){ \
      kf[j][0] = *reinterpret_cast<const short8*>(lKb + (CUR)*8192 + j*2048 + ro0); \
      kf[j][1] = *reinterpret_cast<const short8*>(lKb + (CUR)*8192 + j*2048 + ro1); } \
    short8 vf[4][2]; \
    _Pragma("unroll") for(int jn=0;jn<4;jn++){ \
      { i32x2 vl = *reinterpret_cast<const i32x2*>(lVb + (CUR)*8192 + jn*2048 + vo00); \
        i32x2 vh = *reinterpret_cast<const i32x2*>(lVb + (CUR)*8192 + jn*2048 + vo01); \
        i32x4 vc; vc[0]=vl[0]; vc[1]=vl[1]; vc[2]=vh[0]; vc[3]=vh[1]; \
        vf[jn][0] = __builtin_bit_cast(short8, vc); } \
      { i32x2 vl = *reinterpret_cast<const i32x2*>(lVb + (CUR)*8192 + jn*2048 + vo10); \
        i32x2 vh = *reinterpret_cast<const i32x2*>(lVb + (CUR)*8192 + jn*2048 + vo11); \
        i32x4 vc; vc[0]=vl[0]; vc[1]=vl[1]; vc[2]=vh[0]; vc[3]=vh[1]; \
        vf[jn][1] = __builtin_bit_cast(short8, vc); } } \
    f32x4 s0[4], s1[4]; \
    _Pragma("unroll") for(int j=0;j<4;j++){ \
      f32x4 zz = {}; \
      zz    = __builtin_amdgcn_mfma_f32_16x16x32_bf16(kf[j][0], qA0, zz, 0,0,0); \
      s0[j] = __builtin_amdgcn_mfma_f32_16x16x32_bf16(kf[j][1], qA1, zz, 0,0,0); } \
    _Pragma("unroll") for(int j=0;j<4;j++){ \
      f32x4 zz = {}; \
      zz    = __builtin_amdgcn_mfma_f32_16x16x32_bf16(kf[j][0], qB0, zz, 0,0,0); \
      s1[j] = __builtin_amdgcn_mfma_f32_16x16x32_bf16(kf[j][1], qB1, zz, 0,0,0); } \
    SMPV(s0, lpart[0], oacc[0]); \
    SMPV(s1, lpart[1], oacc[1]); \
    __syncthreads(); \
  } while(0)

  STAGE(0, 0);
  __syncthreads();                             // drains vmcnt before first use

  for(int kt=0; kt<SEQ/64; kt+=2){
    TILE(0, kt, true);
    TILE(1, kt+1, (kt+1) < SEQ/64 - 1);
  }

  // epilogue: reduce row sum across g-lanes (^16, ^32), then O^T/l, f32 store
#pragma unroll
  for(int rg=0;rg<2;rg++){
    float tot = lpart[rg];
    tot += __shfl_xor(tot, 16, 64);
    tot += __shfl_xor(tot, 32, 64);
    float invl = 1.0f / tot;
    int s = qb*128 + w*32 + rg*16 + l16;
    float* orow = out + ((size_t)b*SEQ + s)*HIDDEN + h*HD + 4*g;
#pragma unroll
    for(int jn=0;jn<4;jn++){
      float4 val;
      val.x = oacc[rg][jn][0]*invl; val.y = oacc[rg][jn][1]*invl;
      val.z = oacc[rg][jn][2]*invl; val.w = oacc[rg][jn][3]*invl;
      *reinterpret_cast<float4*>(orow + 16*jn) = val;
    }
  }
#undef STAGE
#undef SMPV
#undef TILE
}

extern "C" void kernel_launch(void* const* d_in, const int* in_sizes, int n_in,
                              void* d_out, int out_size, void* d_ws, size_t ws_size,
                              hipStream_t stream) {
  const float* hs = (const float*)d_in[0];
  const float* Wq = (const float*)d_in[1];
  const float* bq = (const float*)d_in[2];
  const float* Wk = (const float*)d_in[3];
  const float* bk = (const float*)d_in[4];
  const float* Wv = (const float*)d_in[5];
  const float* bv = (const float*)d_in[6];
  float* out = (float*)d_out;

  char* ws = (char*)d_ws;
  unsigned short* Xb = (unsigned short*)ws;                          // 12.6 MB
  unsigned short* Wt = (unsigned short*)(ws + (size_t)12582912);     // 3.5 MB
  unsigned short* Qg = (unsigned short*)(ws + (size_t)16121856);
  unsigned short* Kg = Qg + (size_t)MTOT*HIDDEN;
  unsigned short* Vt = Kg + (size_t)MTOT*HIDDEN;                     // [bh][d][s]

  convert_x_kernel<<<MTOT*HIDDEN/4/256, 256, 0, stream>>>(hs, Xb);
  transpose_w_kernel<<<dim3(24,24,3), 256, 0, stream>>>(Wq, Wk, Wv, Wt);
  gemm_qkv_kernel<<<576, 256, 0, stream>>>(Xb, Wt, bq, bk, bv, Qg, Kg, Vt);
  attn_kernel<<<768, 256, 0, stream>>>(Qg, Kg, Vt, out);
}

// Round 21
// 92.167 us; speedup vs baseline: 1.0431x; 1.0254x over previous
//
#include <hip/hip_runtime.h>
#include <hip/hip_bf16.h>
#include <stdint.h>

typedef __attribute__((ext_vector_type(8))) short short8;
typedef __attribute__((ext_vector_type(4))) float f32x4;
typedef __attribute__((ext_vector_type(4))) int i32x4;
typedef __attribute__((ext_vector_type(2))) int i32x2;
typedef __attribute__((ext_vector_type(4))) unsigned short u16x4;

#define HIDDEN 768
#define HEADS 12
#define HD 64
#define NB 8
#define SEQ 1024
#define MTOT (NB*SEQ)
// Q pre-scale = (1/sqrt(768)) * log2(e): softmax then uses exp2 = raw v_exp_f32
#define QSCALE 0.05205887314427834f

typedef const __attribute__((address_space(1))) uint32_t* gas1_t;
typedef __attribute__((address_space(3))) uint32_t* las3_t;
#define GL_LDS16(g, l) __builtin_amdgcn_global_load_lds((gas1_t)(g), (las3_t)(l), 16, 0, 0)

static __device__ __forceinline__ unsigned short f2bf(float f){
  uint32_t u = __builtin_bit_cast(uint32_t, f);
  u += 0x7fffu + ((u >> 16) & 1u);          // round-to-nearest-even
  return (unsigned short)(u >> 16);
}
static __device__ __forceinline__ float fexp2(float x){
#if __has_builtin(__builtin_amdgcn_exp2f)
  return __builtin_amdgcn_exp2f(x);
#else
  return exp2f(x);
#endif
}

// ---- 1. W[k][n] -> Wt[n][k] bf16 (so GEMM B-frags are contiguous in k) ------
__global__ void transpose_w_kernel(const float* __restrict__ Wq, const float* __restrict__ Wk,
                                   const float* __restrict__ Wv, unsigned short* __restrict__ Wt){
  __shared__ float t[32][33];
  int z = blockIdx.z;
  const float* W = (z==0) ? Wq : ((z==1) ? Wk : Wv);
  unsigned short* o = Wt + (size_t)z * HIDDEN * HIDDEN;
  int n0 = blockIdx.x * 32, k0 = blockIdx.y * 32;
  int x = threadIdx.x & 31, y0 = threadIdx.x >> 5;
#pragma unroll
  for(int p=0;p<4;p++){ int y = y0 + p*8; t[y][x] = W[(size_t)(k0+y)*HIDDEN + n0 + x]; }
  __syncthreads();
#pragma unroll
  for(int p=0;p<4;p++){ int y = y0 + p*8; o[(size_t)(n0+y)*HIDDEN + k0 + x] = f2bf(t[x][y]); }
}

// ---- 2. QKV projection GEMM: r14-verified 128x128/BK=64 2-barrier template,
// ONE new variable: convert_x FUSED into the A-stage. A-tiles reg-staged from
// f32 X (8x float4 issued before B's global_load_lds so HBM latency overlaps),
// v_cvt_pk_bf16_f32, then ds_write_b128 to the SAME swizzled LDS positions
// the gl_lds path produced (write at cb^sw == pre-swizzled source; compute
// reads unchanged). B: global_load_lds, pre-swizzled source. LDS 32 KB.
// grid 1152 1D; XCD-panel mapping: 18 blocks (6 xb x 3 z) sharing an A-panel
// land on one XCD. z==0 writes Q pre-scaled; z==2 writes V TRANSPOSED.
__global__ __launch_bounds__(256, 4) void gemm_qkv_kernel(
    const float* __restrict__ Xf, const unsigned short* __restrict__ Wt,
    const float* __restrict__ bq, const float* __restrict__ bk, const float* __restrict__ bv,
    unsigned short* __restrict__ Qg, unsigned short* __restrict__ Kg, unsigned short* __restrict__ Vt)
{
  __shared__ alignas(16) unsigned short lA[128*64];   // 16 KB
  __shared__ alignas(16) unsigned short lB[128*64];   // 16 KB
  int wgid = blockIdx.x;
  int xcd = wgid & 7, idx = wgid >> 3;       // idx 0..143
  int y = xcd + 8*(idx/18);                  // A-panel id 0..63
  int within = idx % 18;
  int xb = within % 6, z = within / 6;
  const unsigned short* W = Wt + (size_t)z*HIDDEN*HIDDEN;
  const float* bias = (z==0) ? bq : ((z==1) ? bk : bv);
  int m0 = y * 128, n0 = xb * 128;
  int tid = threadIdx.x;
  int w = tid >> 6, lane = tid & 63, l16 = lane & 15, g = lane >> 4;
  int wm = w >> 1, wn = w & 1;               // 2x2 wave grid, 64x64 per wave

  // staging per-lane constants
  int rs = tid >> 3;                         // base row (0..31), +32p per iter
  int cbA = (tid & 7) * 16;                  // A within-row byte (pre-swizzle)
  int cbB = ((((tid & 7) << 4) ^ ((rs & 7) << 4)) >> 1);   // B source elements
  const float* gA = Xf + (size_t)(m0 + rs)*HIDDEN + (tid & 7)*8;
  const unsigned short* gB0 = W + (size_t)(n0 + rs)*HIDDEN + cbB;
  unsigned char* lAw = reinterpret_cast<unsigned char*>(lA);
  const unsigned char* lAb = reinterpret_cast<const unsigned char*>(lA);
  const unsigned char* lBb = reinterpret_cast<const unsigned char*>(lB);

  f32x4 acc[4][4] = {};
  for(int kt=0; kt<HIDDEN; kt+=64){
    __syncthreads();
    // A: issue all 8 f32 loads first (latency overlaps B's gl_lds issue)
    float4 a0[4], a1[4];
#pragma unroll
    for(int p=0;p<4;p++){
      const float4* s = reinterpret_cast<const float4*>(gA + (size_t)p*32*HIDDEN + kt);
      a0[p] = s[0]; a1[p] = s[1];
    }
    // B: async global->LDS (pre-swizzled source)
#pragma unroll
    for(int p=0;p<4;p++)
      GL_LDS16(gB0 + (size_t)p*32*HIDDEN + kt, lB + p*2048 + w*512);
    // A: convert + swizzled LDS write (row r, byte cbA^((r&7)<<4))
#pragma unroll
    for(int p=0;p<4;p++){
      int r = p*32 + rs;
      i32x4 pk;
      asm("v_cvt_pk_bf16_f32 %0, %1, %2" : "=v"(pk[0]) : "v"(a0[p].x), "v"(a0[p].y));
      asm("v_cvt_pk_bf16_f32 %0, %1, %2" : "=v"(pk[1]) : "v"(a0[p].z), "v"(a0[p].w));
      asm("v_cvt_pk_bf16_f32 %0, %1, %2" : "=v"(pk[2]) : "v"(a1[p].x), "v"(a1[p].y));
      asm("v_cvt_pk_bf16_f32 %0, %1, %2" : "=v"(pk[3]) : "v"(a1[p].z), "v"(a1[p].w));
      *reinterpret_cast<i32x4*>(lAw + r*128 + (cbA ^ ((r&7)<<4))) = pk;
    }
    __syncthreads();   // drains vmcnt (B gl_lds) + lgkm (A ds_writes)
#pragma unroll
    for(int kk=0;kk<2;kk++){
      short8 af[4], bf[4];
#pragma unroll
      for(int i=0;i<4;i++){
        int row = wm*64 + i*16 + l16;
        af[i] = *reinterpret_cast<const short8*>(
            lAb + row*128 + ((kk*64 + g*16) ^ ((row&7)<<4)));
      }
#pragma unroll
      for(int j=0;j<4;j++){
        int row = wn*64 + j*16 + l16;
        bf[j] = *reinterpret_cast<const short8*>(
            lBb + row*128 + ((kk*64 + g*16) ^ ((row&7)<<4)));
      }
#pragma unroll
      for(int i=0;i<4;i++)
#pragma unroll
        for(int j=0;j<4;j++)
          acc[i][j] = __builtin_amdgcn_mfma_f32_16x16x32_bf16(af[i], bf[j], acc[i][j], 0, 0, 0);
    }
  }
  if(z == 2){
    // V epilogue: bias then TRANSPOSED write Vt[bh][d][s], 4 consecutive s/lane
#pragma unroll
    for(int i=0;i<4;i++){
      int mb = m0 + wm*64 + i*16 + g*4;
      int b = mb >> 10, s = mb & 1023;       // all 4 rows stay in one (b, s+0..3)
#pragma unroll
      for(int j=0;j<4;j++){
        int n = n0 + wn*64 + j*16 + l16;
        float bi = bias[n];
        int h = n >> 6, d = n & 63;
        u16x4 pk;
#pragma unroll
        for(int r=0;r<4;r++) pk[r] = f2bf(acc[i][j][r] + bi);
        *reinterpret_cast<u16x4*>(Vt + ((size_t)(b*HEADS + h)*HD + d)*SEQ + s) = pk;
      }
    }
  } else {
    unsigned short* out = (z==0) ? Qg : Kg;
#pragma unroll
    for(int i=0;i<4;i++){
      int mb = m0 + wm*64 + i*16 + g*4;
#pragma unroll
      for(int j=0;j<4;j++){
        int n = n0 + wn*64 + j*16 + l16;       // D col = lane&15
        float bi = bias[n];
        int h = n >> 6, d = n & 63;
#pragma unroll
        for(int r=0;r<4;r++){                  // D row = 4*(lane>>4)+r
          int m = mb + r;
          int b = m >> 10, s = m & 1023;
          float cv = acc[i][j][r] + bi;
          if(z == 0) cv *= QSCALE;
          out[((size_t)(b*HEADS + h)*SEQ + s)*HD + d] = f2bf(cv);
        }
      }
    }
  }
}

// ---- 3. flash attention: QBLK=128/block, 4 waves x 32 rows, dbuf K/V --------
// (verified round 14 — unchanged) SWAPPED QK^T: S^T = mfma(A=K, B=Q), q
// lane-local; P^T B-frag lane-local via sigma-permuted contraction axis;
// V^T A-frag reads absorb sigma as two ds_read_b64 per (jn,m); XOR swizzle
// over the FULL within-row offset. Row-sum reduced once in the epilogue.
__global__ __launch_bounds__(256, 3) void attn_kernel(
    const unsigned short* __restrict__ Qg, const unsigned short* __restrict__ Kg,
    const unsigned short* __restrict__ Vt, float* __restrict__ out)
{
  __shared__ alignas(16) unsigned short lK[2][64*64];  // [key][d], XOR-swizzled
  __shared__ alignas(16) unsigned short lV[2][64*64];  // [d][key], XOR-swizzled
  int wgid = blockIdx.x;
  int xcd = wgid & 7, ix = wgid >> 3;          // xcd = dispatch%8 heuristic
  int bh = xcd*12 + (ix >> 3), qb = ix & 7;    // 12 heads per XCD (3MB K/V < L2)
  int b = bh / HEADS, h = bh % HEADS;
  int tid = threadIdx.x, w = tid >> 6, lane = tid & 63, l16 = lane & 15, g = lane >> 4;

  // Q B-frags (2 row-groups x 2 d-halves) in registers for whole kernel
  const unsigned short* Qbase = Qg + ((size_t)bh*SEQ + qb*128 + w*32)*HD;
  short8 qA0 = *reinterpret_cast<const short8*>(Qbase + l16*HD + g*8);
  short8 qA1 = *reinterpret_cast<const short8*>(Qbase + l16*HD + 32 + g*8);
  short8 qB0 = *reinterpret_cast<const short8*>(Qbase + (16+l16)*HD + g*8);
  short8 qB1 = *reinterpret_cast<const short8*>(Qbase + (16+l16)*HD + 32 + g*8);

  f32x4 oacc[2][4] = {};                       // O^T: [rg][jn] d=16jn+4g+r, q=l16
  float lpart[2] = {0.f, 0.f};                 // per-lane partial row sum (q=l16)

  // per-lane constant LDS addresses (all loop offsets become immediates)
  int sw = (l16 & 7) << 4;
  int ro0 = l16*128 + ((g*16) ^ sw);           // K-frag byte offset, d-half 0
  int ro1 = l16*128 + ((64 + g*16) ^ sw);      // K-frag byte offset, d-half 1
  // V-frag b64 offsets: sigma absorbed; XOR over the FULL within-row offset
  int vo00 = l16*128 + ((      8*g) ^ sw);     // m=0, keys 4g+0..3
  int vo01 = l16*128 + ((32  + 8*g) ^ sw);     // m=0, keys 16+4g+0..3
  int vo10 = l16*128 + ((64  + 8*g) ^ sw);     // m=1, keys 32+4g+0..3
  int vo11 = l16*128 + ((96  + 8*g) ^ sw);     // m=1, keys 48+4g+0..3
  const unsigned char* lKb = reinterpret_cast<const unsigned char*>(&lK[0][0]);
  const unsigned char* lVb = reinterpret_cast<const unsigned char*>(&lV[0][0]);

  // per-lane constant staging addresses (source pre-swizzled: byte^=(row&7)<<4)
  int r0 = tid >> 3;
  int cb0 = (((tid & 7) << 4) ^ ((r0 & 7) << 4)) >> 1;             // elements
  const unsigned short* gK0 = Kg + (size_t)bh*SEQ*HD + r0*HD + cb0;
  const unsigned short* gV0 = Vt + (size_t)bh*HD*SEQ + r0*SEQ + cb0;

#define STAGE(B, t) do { \
    GL_LDS16(gK0 + (t)*4096,          &lK[B][0] + w*512); \
    GL_LDS16(gK0 + (t)*4096 + 2048,   &lK[B][0] + 2048 + w*512); \
    GL_LDS16(gV0 + (t)*64,            &lV[B][0] + w*512); \
    GL_LDS16(gV0 + (t)*64 + 32*SEQ,   &lV[B][0] + 2048 + w*512); \
  } while(0)

  // exp2 + lane-local P^T frag build + PV for one row-group
#define SMPV(SREG, LP, OA) do { \
    int Wlo[4], Whi[4]; \
    _Pragma("unroll") for(int j=0;j<4;j++){ \
      float p0=fexp2(SREG[j][0]), p1=fexp2(SREG[j][1]); \
      float p2=fexp2(SREG[j][2]), p3=fexp2(SREG[j][3]); \
      LP += (p0+p1)+(p2+p3); \
      asm("v_cvt_pk_bf16_f32 %0, %1, %2" : "=v"(Wlo[j]) : "v"(p0), "v"(p1)); \
      asm("v_cvt_pk_bf16_f32 %0, %1, %2" : "=v"(Whi[j]) : "v"(p2), "v"(p3)); } \
    _Pragma("unroll") for(int m=0;m<2;m++){ \
      i32x4 cc; cc[0]=Wlo[2*m]; cc[1]=Whi[2*m]; cc[2]=Wlo[2*m+1]; cc[3]=Whi[2*m+1]; \
      short8 pB = __builtin_bit_cast(short8, cc); \
      _Pragma("unroll") for(int jn=0;jn<4;jn++) \
        OA[jn] = __builtin_amdgcn_mfma_f32_16x16x32_bf16(vf[jn][m], pB, OA[jn], 0,0,0); } \
  } while(0)

#define TILE(CUR, kt, HAS_NEXT) do { \
    if(HAS_NEXT) STAGE((CUR)^1, (kt)+1); \
    short8 kf[4][2]; \
    _Pragma("unroll") for(int j=0;j<4;j++){ \
      kf[j][0] = *reinterpret_cast<const short8*>(lKb + (CUR)*8192 + j*2048 + ro0); \
      kf[j][1] = *reinterpret_cast<const short8*>(lKb + (CUR)*8192 + j*2048 + ro1); } \
    short8 vf[4][2]; \
    _Pragma("unroll") for(int jn=0;jn<4;jn++){ \
      { i32x2 vl = *reinterpret_cast<const i32x2*>(lVb + (CUR)*8192 + jn*2048 + vo00); \
        i32x2 vh = *reinterpret_cast<const i32x2*>(lVb + (CUR)*8192 + jn*2048 + vo01); \
        i32x4 vc; vc[0]=vl[0]; vc[1]=vl[1]; vc[2]=vh[0]; vc[3]=vh[1]; \
        vf[jn][0] = __builtin_bit_cast(short8, vc); } \
      { i32x2 vl = *reinterpret_cast<const i32x2*>(lVb + (CUR)*8192 + jn*2048 + vo10); \
        i32x2 vh = *reinterpret_cast<const i32x2*>(lVb + (CUR)*8192 + jn*2048 + vo11); \
        i32x4 vc; vc[0]=vl[0]; vc[1]=vl[1]; vc[2]=vh[0]; vc[3]=vh[1]; \
        vf[jn][1] = __builtin_bit_cast(short8, vc); } } \
    f32x4 s0[4], s1[4]; \
    _Pragma("unroll") for(int j=0;j<4;j++){ \
      f32x4 zz = {}; \
      zz    = __builtin_amdgcn_mfma_f32_16x16x32_bf16(kf[j][0], qA0, zz, 0,0,0); \
      s0[j] = __builtin_amdgcn_mfma_f32_16x16x32_bf16(kf[j][1], qA1, zz, 0,0,0); } \
    _Pragma("unroll") for(int j=0;j<4;j++){ \
      f32x4 zz = {}; \
      zz    = __builtin_amdgcn_mfma_f32_16x16x32_bf16(kf[j][0], qB0, zz, 0,0,0); \
      s1[j] = __builtin_amdgcn_mfma_f32_16x16x32_bf16(kf[j][1], qB1, zz, 0,0,0); } \
    SMPV(s0, lpart[0], oacc[0]); \
    SMPV(s1, lpart[1], oacc[1]); \
    __syncthreads(); \
  } while(0)

  STAGE(0, 0);
  __syncthreads();                             // drains vmcnt before first use

  for(int kt=0; kt<SEQ/64; kt+=2){
    TILE(0, kt, true);
    TILE(1, kt+1, (kt+1) < SEQ/64 - 1);
  }

  // epilogue: reduce row sum across g-lanes (^16, ^32), then O^T/l, f32 store
#pragma unroll
  for(int rg=0;rg<2;rg++){
    float tot = lpart[rg];
    tot += __shfl_xor(tot, 16, 64);
    tot += __shfl_xor(tot, 32, 64);
    float invl = 1.0f / tot;
    int s = qb*128 + w*32 + rg*16 + l16;
    float* orow = out + ((size_t)b*SEQ + s)*HIDDEN + h*HD + 4*g;
#pragma unroll
    for(int jn=0;jn<4;jn++){
      float4 val;
      val.x = oacc[rg][jn][0]*invl; val.y = oacc[rg][jn][1]*invl;
      val.z = oacc[rg][jn][2]*invl; val.w = oacc[rg][jn][3]*invl;
      *reinterpret_cast<float4*>(orow + 16*jn) = val;
    }
  }
#undef STAGE
#undef SMPV
#undef TILE
}

extern "C" void kernel_launch(void* const* d_in, const int* in_sizes, int n_in,
                              void* d_out, int out_size, void* d_ws, size_t ws_size,
                              hipStream_t stream) {
  const float* hs = (const float*)d_in[0];
  const float* Wq = (const float*)d_in[1];
  const float* bq = (const float*)d_in[2];
  const float* Wk = (const float*)d_in[3];
  const float* bk = (const float*)d_in[4];
  const float* Wv = (const float*)d_in[5];
  const float* bv = (const float*)d_in[6];
  float* out = (float*)d_out;

  char* ws = (char*)d_ws;
  unsigned short* Wt = (unsigned short*)ws;                          // 3.5 MB
  unsigned short* Qg = (unsigned short*)(ws + (size_t)4*1024*1024);
  unsigned short* Kg = Qg + (size_t)MTOT*HIDDEN;
  unsigned short* Vt = Kg + (size_t)MTOT*HIDDEN;                     // [bh][d][s]

  transpose_w_kernel<<<dim3(24,24,3), 256, 0, stream>>>(Wq, Wk, Wv, Wt);
  gemm_qkv_kernel<<<1152, 256, 0, stream>>>(hs, Wt, bq, bk, bv, Qg, Kg, Vt);
  attn_kernel<<<768, 256, 0, stream>>>(Qg, Kg, Vt, out);
}

// Round 23
// 86.443 us; speedup vs baseline: 1.1122x; 1.0662x over previous
//
#include <hip/hip_runtime.h>
#include <hip/hip_bf16.h>
#include <stdint.h>

typedef __attribute__((ext_vector_type(8))) short short8;
typedef __attribute__((ext_vector_type(4))) float f32x4;
typedef __attribute__((ext_vector_type(4))) int i32x4;
typedef __attribute__((ext_vector_type(2))) int i32x2;
typedef __attribute__((ext_vector_type(4))) unsigned short u16x4;

#define HIDDEN 768
#define HEADS 12
#define HD 64
#define NB 8
#define SEQ 1024
#define MTOT (NB*SEQ)
// Q pre-scale = (1/sqrt(768)) * log2(e): softmax then uses exp2 = raw v_exp_f32
#define QSCALE 0.05205887314427834f
// convert blocks: MTOT*HIDDEN/4/256 = 6144 (r22 crash was 12288 -> OOB)
#define NCVT 6144

typedef const __attribute__((address_space(1))) uint32_t* gas1_t;
typedef __attribute__((address_space(3))) uint32_t* las3_t;
#define GL_LDS16(g, l) __builtin_amdgcn_global_load_lds((gas1_t)(g), (las3_t)(l), 16, 0, 0)

static __device__ __forceinline__ unsigned short f2bf(float f){
  uint32_t u = __builtin_bit_cast(uint32_t, f);
  u += 0x7fffu + ((u >> 16) & 1u);          // round-to-nearest-even
  return (unsigned short)(u >> 16);
}
static __device__ __forceinline__ float fexp2(float x){
#if __has_builtin(__builtin_amdgcn_exp2f)
  return __builtin_amdgcn_exp2f(x);
#else
  return exp2f(x);
#endif
}

// ---- 1. prep: fp32->bf16 convert of X (blocks 0..6143) + W transpose --------
// (blocks 6144..7871 = 24x24x3). Merged to save one launch gap.
__global__ void prep_kernel(const float* __restrict__ x, unsigned short* __restrict__ xb,
                            const float* __restrict__ Wq, const float* __restrict__ Wk,
                            const float* __restrict__ Wv, unsigned short* __restrict__ Wt){
  __shared__ float t[32][33];
  int bid = blockIdx.x;
  if(bid < NCVT){
    int i = bid * 256 + threadIdx.x;             // one float4 per thread
    float4 v = reinterpret_cast<const float4*>(x)[i];
    u16x4 o;
    o[0]=f2bf(v.x); o[1]=f2bf(v.y); o[2]=f2bf(v.z); o[3]=f2bf(v.w);
    reinterpret_cast<u16x4*>(xb)[i] = o;
    return;
  }
  int b2 = bid - NCVT;                           // 24 x 24 x 3 transpose grid
  int xg = b2 % 24, yg = (b2/24) % 24, z = b2/576;
  const float* W = (z==0) ? Wq : ((z==1) ? Wk : Wv);
  unsigned short* o = Wt + (size_t)z * HIDDEN * HIDDEN;
  int n0 = xg * 32, k0 = yg * 32;
  int xl = threadIdx.x & 31, y0 = threadIdx.x >> 5;
#pragma unroll
  for(int p=0;p<4;p++){ int y = y0 + p*8; t[y][xl] = W[(size_t)(k0+y)*HIDDEN + n0 + xl]; }
  __syncthreads();
#pragma unroll
  for(int p=0;p<4;p++){ int y = y0 + p*8; o[(size_t)(n0+y)*HIDDEN + k0 + xl] = f2bf(t[xl][y]); }
}

// ---- 2. QKV projection GEMM (ROUND-14 VERIFIED, byte-identical) -------------
// C = X @ W + b; 128x128 tile, BK=64, grid 1152 1D. XCD-panel mapping: all 18
// blocks (6 xb x 3 z) sharing an A-panel land on one XCD. LDS tiles [128][64]
// bf16 (128B rows): both-sides XOR swizzle byte^=(row&7)<<4 (pre-swizzled
// global_load_lds source + swizzled ds_read). z==0 writes Q pre-scaled by
// QSCALE; z==2 writes V TRANSPOSED ([bh][d][s]).
__global__ __launch_bounds__(256, 4) void gemm_qkv_kernel(
    const unsigned short* __restrict__ Xb, const unsigned short* __restrict__ Wt,
    const float* __restrict__ bq, const float* __restrict__ bk, const float* __restrict__ bv,
    unsigned short* __restrict__ Qg, unsigned short* __restrict__ Kg, unsigned short* __restrict__ Vt)
{
  __shared__ alignas(16) unsigned short lA[128*64];   // 16 KB
  __shared__ alignas(16) unsigned short lB[128*64];   // 16 KB
  int wgid = blockIdx.x;
  int xcd = wgid & 7, idx = wgid >> 3;       // idx 0..143
  int y = xcd + 8*(idx/18);                  // A-panel id 0..63
  int within = idx % 18;
  int xb = within % 6, z = within / 6;
  const unsigned short* W = Wt + (size_t)z*HIDDEN*HIDDEN;
  const float* bias = (z==0) ? bq : ((z==1) ? bk : bv);
  int m0 = y * 128, n0 = xb * 128;
  int tid = threadIdx.x;
  int w = tid >> 6, lane = tid & 63, l16 = lane & 15, g = lane >> 4;
  int wm = w >> 1, wn = w & 1;               // 2x2 wave grid, 64x64 per wave
  f32x4 acc[4][4] = {};
  for(int kt=0; kt<HIDDEN; kt+=64){
    __syncthreads();
#pragma unroll
    for(int p=0;p<4;p++){
      int t2 = p*256 + tid;
      int r = t2 >> 3;                                // tile row (128B rows)
      int cb = (((t2 & 7) << 4) ^ ((r & 7) << 4));    // swizzled source byte
      GL_LDS16(Xb + (size_t)(m0 + r)*HIDDEN + kt + (cb >> 1), lA + p*2048 + w*512);
      GL_LDS16(W  + (size_t)(n0 + r)*HIDDEN + kt + (cb >> 1), lB + p*2048 + w*512);
    }
    __syncthreads();
#pragma unroll
    for(int kk=0;kk<2;kk++){
      short8 af[4], bf[4];
#pragma unroll
      for(int i=0;i<4;i++){
        int row = wm*64 + i*16 + l16;
        af[i] = *reinterpret_cast<const short8*>(
            reinterpret_cast<const unsigned char*>(lA) + row*128 + ((kk*64 + g*16) ^ ((row&7)<<4)));
      }
#pragma unroll
      for(int j=0;j<4;j++){
        int row = wn*64 + j*16 + l16;
        bf[j] = *reinterpret_cast<const short8*>(
            reinterpret_cast<const unsigned char*>(lB) + row*128 + ((kk*64 + g*16) ^ ((row&7)<<4)));
      }
#pragma unroll
      for(int i=0;i<4;i++)
#pragma unroll
        for(int j=0;j<4;j++)
          acc[i][j] = __builtin_amdgcn_mfma_f32_16x16x32_bf16(af[i], bf[j], acc[i][j], 0, 0, 0);
    }
  }
  if(z == 2){
    // V epilogue: bias then TRANSPOSED write Vt[bh][d][s], 4 consecutive s/lane
#pragma unroll
    for(int i=0;i<4;i++){
      int mb = m0 + wm*64 + i*16 + g*4;
      int b = mb >> 10, s = mb & 1023;       // all 4 rows stay in one (b, s+0..3)
#pragma unroll
      for(int j=0;j<4;j++){
        int n = n0 + wn*64 + j*16 + l16;
        float bi = bias[n];
        int h = n >> 6, d = n & 63;
        u16x4 pk;
#pragma unroll
        for(int r=0;r<4;r++) pk[r] = f2bf(acc[i][j][r] + bi);
        *reinterpret_cast<u16x4*>(Vt + ((size_t)(b*HEADS + h)*HD + d)*SEQ + s) = pk;
      }
    }
  } else {
    unsigned short* out = (z==0) ? Qg : Kg;
#pragma unroll
    for(int i=0;i<4;i++){
      int mb = m0 + wm*64 + i*16 + g*4;
#pragma unroll
      for(int j=0;j<4;j++){
        int n = n0 + wn*64 + j*16 + l16;       // D col = lane&15
        float bi = bias[n];
        int h = n >> 6, d = n & 63;
#pragma unroll
        for(int r=0;r<4;r++){                  // D row = 4*(lane>>4)+r
          int m = mb + r;
          int b = m >> 10, s = m & 1023;
          float cv = acc[i][j][r] + bi;
          if(z == 0) cv *= QSCALE;
          out[((size_t)(b*HEADS + h)*SEQ + s)*HD + d] = f2bf(cv);
        }
      }
    }
  }
}

// ---- 3. flash attention: QBLK=128/block, 4 waves x 32 rows, dbuf K/V --------
// (verified round 14 — unchanged) SWAPPED QK^T: S^T = mfma(A=K, B=Q), q
// lane-local; P^T B-frag lane-local via sigma-permuted contraction axis;
// V^T A-frag reads absorb sigma as two ds_read_b64 per (jn,m); XOR swizzle
// over the FULL within-row offset. Row-sum reduced once in the epilogue.
__global__ __launch_bounds__(256, 3) void attn_kernel(
    const unsigned short* __restrict__ Qg, const unsigned short* __restrict__ Kg,
    const unsigned short* __restrict__ Vt, float* __restrict__ out)
{
  __shared__ alignas(16) unsigned short lK[2][64*64];  // [key][d], XOR-swizzled
  __shared__ alignas(16) unsigned short lV[2][64*64];  // [d][key], XOR-swizzled
  int wgid = blockIdx.x;
  int xcd = wgid & 7, ix = wgid >> 3;          // xcd = dispatch%8 heuristic
  int bh = xcd*12 + (ix >> 3), qb = ix & 7;    // 12 heads per XCD (3MB K/V < L2)
  int b = bh / HEADS, h = bh % HEADS;
  int tid = threadIdx.x, w = tid >> 6, lane = tid & 63, l16 = lane & 15, g = lane >> 4;

  // Q B-frags (2 row-groups x 2 d-halves) in registers for whole kernel
  const unsigned short* Qbase = Qg + ((size_t)bh*SEQ + qb*128 + w*32)*HD;
  short8 qA0 = *reinterpret_cast<const short8*>(Qbase + l16*HD + g*8);
  short8 qA1 = *reinterpret_cast<const short8*>(Qbase + l16*HD + 32 + g*8);
  short8 qB0 = *reinterpret_cast<const short8*>(Qbase + (16+l16)*HD + g*8);
  short8 qB1 = *reinterpret_cast<const short8*>(Qbase + (16+l16)*HD + 32 + g*8);

  f32x4 oacc[2][4] = {};                       // O^T: [rg][jn] d=16jn+4g+r, q=l16
  float lpart[2] = {0.f, 0.f};                 // per-lane partial row sum (q=l16)

  // per-lane constant LDS addresses (all loop offsets become immediates)
  int sw = (l16 & 7) << 4;
  int ro0 = l16*128 + ((g*16) ^ sw);           // K-frag byte offset, d-half 0
  int ro1 = l16*128 + ((64 + g*16) ^ sw);      // K-frag byte offset, d-half 1
  // V-frag b64 offsets: sigma absorbed; XOR over the FULL within-row offset
  int vo00 = l16*128 + ((      8*g) ^ sw);     // m=0, keys 4g+0..3
  int vo01 = l16*128 + ((32  + 8*g) ^ sw);     // m=0, keys 16+4g+0..3
  int vo10 = l16*128 + ((64  + 8*g) ^ sw);     // m=1, keys 32+4g+0..3
  int vo11 = l16*128 + ((96  + 8*g) ^ sw);     // m=1, keys 48+4g+0..3
  const unsigned char* lKb = reinterpret_cast<const unsigned char*>(&lK[0][0]);
  const unsigned char* lVb = reinterpret_cast<const unsigned char*>(&lV[0][0]);

  // per-lane constant staging addresses (source pre-swizzled: byte^=(row&7)<<4)
  int r0 = tid >> 3;
  int cb0 = (((tid & 7) << 4) ^ ((r0 & 7) << 4)) >> 1;             // elements
  const unsigned short* gK0 = Kg + (size_t)bh*SEQ*HD + r0*HD + cb0;
  const unsigned short* gV0 = Vt + (size_t)bh*HD*SEQ + r0*SEQ + cb0;

#define STAGE(B, t) do { \
    GL_LDS16(gK0 + (t)*4096,          &lK[B][0] + w*512); \
    GL_LDS16(gK0 + (t)*4096 + 2048,   &lK[B][0] + 2048 + w*512); \
    GL_LDS16(gV0 + (t)*64,            &lV[B][0] + w*512); \
    GL_LDS16(gV0 + (t)*64 + 32*SEQ,   &lV[B][0] + 2048 + w*512); \
  } while(0)

  // exp2 + lane-local P^T frag build + PV for one row-group
#define SMPV(SREG, LP, OA) do { \
    int Wlo[4], Whi[4]; \
    _Pragma("unroll") for(int j=0;j<4;j++){ \
      float p0=fexp2(SREG[j][0]), p1=fexp2(SREG[j][1]); \
      float p2=fexp2(SREG[j][2]), p3=fexp2(SREG[j][3]); \
      LP += (p0+p1)+(p2+p3); \
      asm("v_cvt_pk_bf16_f32 %0, %1, %2" : "=v"(Wlo[j]) : "v"(p0), "v"(p1)); \
      asm("v_cvt_pk_bf16_f32 %0, %1, %2" : "=v"(Whi[j]) : "v"(p2), "v"(p3)); } \
    _Pragma("unroll") for(int m=0;m<2;m++){ \
      i32x4 cc; cc[0]=Wlo[2*m]; cc[1]=Whi[2*m]; cc[2]=Wlo[2*m+1]; cc[3]=Whi[2*m+1]; \
      short8 pB = __builtin_bit_cast(short8, cc); \
      _Pragma("unroll") for(int jn=0;jn<4;jn++) \
        OA[jn] = __builtin_amdgcn_mfma_f32_16x16x32_bf16(vf[jn][m], pB, OA[jn], 0,0,0); } \
  } while(0)

#define TILE(CUR, kt, HAS_NEXT) do { \
    if(HAS_NEXT) STAGE((CUR)^1, (kt)+1); \
    short8 kf[4][2]; \
    _Pragma("unroll") for(int j=0;j<4;j++){ \
      kf[j][0] = *reinterpret_cast<const short8*>(lKb + (CUR)*8192 + j*2048 + ro0); \
      kf[j][1] = *reinterpret_cast<const short8*>(lKb + (CUR)*8192 + j*2048 + ro1); } \
    short8 vf[4][2]; \
    _Pragma("unroll") for(int jn=0;jn<4;jn++){ \
      { i32x2 vl = *reinterpret_cast<const i32x2*>(lVb + (CUR)*8192 + jn*2048 + vo00); \
        i32x2 vh = *reinterpret_cast<const i32x2*>(lVb + (CUR)*8192 + jn*2048 + vo01); \
        i32x4 vc; vc[0]=vl[0]; vc[1]=vl[1]; vc[2]=vh[0]; vc[3]=vh[1]; \
        vf[jn][0] = __builtin_bit_cast(short8, vc); } \
      { i32x2 vl = *reinterpret_cast<const i32x2*>(lVb + (CUR)*8192 + jn*2048 + vo10); \
        i32x2 vh = *reinterpret_cast<const i32x2*>(lVb + (CUR)*8192 + jn*2048 + vo11); \
        i32x4 vc; vc[0]=vl[0]; vc[1]=vl[1]; vc[2]=vh[0]; vc[3]=vh[1]; \
        vf[jn][1] = __builtin_bit_cast(short8, vc); } } \
    f32x4 s0[4], s1[4]; \
    _Pragma("unroll") for(int j=0;j<4;j++){ \
      f32x4 zz = {}; \
      zz    = __builtin_amdgcn_mfma_f32_16x16x32_bf16(kf[j][0], qA0, zz, 0,0,0); \
      s0[j] = __builtin_amdgcn_mfma_f32_16x16x32_bf16(kf[j][1], qA1, zz, 0,0,0); } \
    _Pragma("unroll") for(int j=0;j<4;j++){ \
      f32x4 zz = {}; \
      zz    = __builtin_amdgcn_mfma_f32_16x16x32_bf16(kf[j][0], qB0, zz, 0,0,0); \
      s1[j] = __builtin_amdgcn_mfma_f32_16x16x32_bf16(kf[j][1], qB1, zz, 0,0,0); } \
    SMPV(s0, lpart[0], oacc[0]); \
    SMPV(s1, lpart[1], oacc[1]); \
    __syncthreads(); \
  } while(0)

  STAGE(0, 0);
  __syncthreads();                             // drains vmcnt before first use

  for(int kt=0; kt<SEQ/64; kt+=2){
    TILE(0, kt, true);
    TILE(1, kt+1, (kt+1) < SEQ/64 - 1);
  }

  // epilogue: reduce row sum across g-lanes (^16, ^32), then O^T/l, f32 store
#pragma unroll
  for(int rg=0;rg<2;rg++){
    float tot = lpart[rg];
    tot += __shfl_xor(tot, 16, 64);
    tot += __shfl_xor(tot, 32, 64);
    float invl = 1.0f / tot;
    int s = qb*128 + w*32 + rg*16 + l16;
    float* orow = out + ((size_t)b*SEQ + s)*HIDDEN + h*HD + 4*g;
#pragma unroll
    for(int jn=0;jn<4;jn++){
      float4 val;
      val.x = oacc[rg][jn][0]*invl; val.y = oacc[rg][jn][1]*invl;
      val.z = oacc[rg][jn][2]*invl; val.w = oacc[rg][jn][3]*invl;
      *reinterpret_cast<float4*>(orow + 16*jn) = val;
    }
  }
#undef STAGE
#undef SMPV
#undef TILE
}

extern "C" void kernel_launch(void* const* d_in, const int* in_sizes, int n_in,
                              void* d_out, int out_size, void* d_ws, size_t ws_size,
                              hipStream_t stream) {
  const float* hs = (const float*)d_in[0];
  const float* Wq = (const float*)d_in[1];
  const float* bq = (const float*)d_in[2];
  const float* Wk = (const float*)d_in[3];
  const float* bk = (const float*)d_in[4];
  const float* Wv = (const float*)d_in[5];
  const float* bv = (const float*)d_in[6];
  float* out = (float*)d_out;

  char* ws = (char*)d_ws;
  unsigned short* Xb = (unsigned short*)ws;                          // 12.6 MB
  unsigned short* Wt = (unsigned short*)(ws + (size_t)12582912);     // 3.5 MB
  unsigned short* Qg = (unsigned short*)(ws + (size_t)16121856);
  unsigned short* Kg = Qg + (size_t)MTOT*HIDDEN;
  unsigned short* Vt = Kg + (size_t)MTOT*HIDDEN;                     // [bh][d][s]

  prep_kernel<<<NCVT + 1728, 256, 0, stream>>>(hs, Xb, Wq, Wk, Wv, Wt);
  gemm_qkv_kernel<<<1152, 256, 0, stream>>>(Xb, Wt, bq, bk, bv, Qg, Kg, Vt);
  attn_kernel<<<768, 256, 0, stream>>>(Qg, Kg, Vt, out);
}